// Round 12
// baseline (5728.906 us; speedup 1.0000x reference)
//
#include <hip/hip_runtime.h>
#include <math.h>

#define DD 64
#define BIGF 1.0e9f

typedef float vcol_t __attribute__((ext_vector_type(64)));

// uniform-lane broadcast via v_readlane (no DS pipe)
__device__ __forceinline__ float bcastf(float x, int lane) {
    return __builtin_bit_cast(float, __builtin_amdgcn_readlane(__builtin_bit_cast(int, x), lane));
}
__device__ __forceinline__ int bcasti(int x, int lane) {
    return __builtin_amdgcn_readlane(x, lane);
}

// full-wave64 min via DPP (pure VALU): row_shr 1/2/4/8 + row_bcast15/31.
// bound_ctrl=false: invalid source lanes keep old value (harmless for min).
__device__ __forceinline__ float wave_min64(float x) {
#define STEPD(ctrl)                                                                \
    {                                                                              \
        int _t = __builtin_amdgcn_update_dpp(__builtin_bit_cast(int, x),           \
                                             __builtin_bit_cast(int, x),           \
                                             ctrl, 0xF, 0xF, false);               \
        x = fminf(x, __builtin_bit_cast(float, _t));                               \
    }
    STEPD(0x111)  // row_shr:1
    STEPD(0x112)  // row_shr:2
    STEPD(0x114)  // row_shr:4
    STEPD(0x118)  // row_shr:8
    STEPD(0x142)  // row_bcast:15
    STEPD(0x143)  // row_bcast:31
#undef STEPD
    return bcastf(x, 63);
}

// ---- fast f64 log (r9..r11, proven absmax 0.0): table + degree-6 log1p ----
__device__ __forceinline__ double fast_log(double d, const double2* __restrict__ tbl) {
    long long bits = __double_as_longlong(d);
    int e = (int)(bits >> 52) - 1023;
    double m = __longlong_as_double((bits & 0x000FFFFFFFFFFFFFLL) | 0x3FF0000000000000LL);
    int idx = (int)(bits >> 45) & 127;
    double2 t = tbl[idx];                 // t.x = inv_c (rounded), t.y = -log(inv_c)
    double r  = fma(m, t.x, -1.0);
    double r2 = r * r;
    double q = fma(r, -1.0 / 6.0, 0.2);
    q = fma(q, r, -0.25);
    q = fma(q, r, 1.0 / 3.0);
    q = fma(q, r, -0.5);
    double res = fma(q, r2, r);           // log1p(r)
    return fma((double)e, 0.69314718055994530942, t.y + res);
}

// ---- Fused register-resident JV solver: one wave per block, one sample. ----
// Lane l owns column j=l+1 state (v,minv,way,p,used), row r=l+1 dual u, AND
// the full cost column cost[*][l] in a 64-wide per-lane register vector.
// Row reads become uniform-index dynamic extracts (v_movrels, ~10cy) instead
// of global loads (~600cy L3) - the r3..r11 latency bottleneck is deleted.
// Cost values are computed in the prologue with the bit-exact r9 fast_log
// ops; the JV trajectory is the literal reference op sequence (r11).
__global__ __launch_bounds__(64, 4) void lap64_fused(
    const float* __restrict__ gamma,
    const float* __restrict__ uin,
    float* __restrict__ out,
    int nsamp)
{
    __shared__ double2 tbl[128];
    {
        int t = threadIdx.x;
        // 64 threads build 128 entries (2 each)
        for (int k = t; k < 128; k += 64) {
            double cc = 1.0 + (double)(2 * k + 1) * (1.0 / 256.0);
            double inv = 1.0 / cc;
            tbl[k].x = inv;
            tbl[k].y = -log(inv);
        }
    }
    __syncthreads();

    const int l = threadIdx.x & 63;
    const int b = blockIdx.x;
    if (b >= nsamp) return;
    const float* ub = uin + (size_t)b * (DD * DD);

    // ---- prologue: compute this sample's cost column into registers ----
    const float lo = 1e-20f;
    const float hi = (float)(1.0 - 1e-7);
    vcol_t colv;
#pragma unroll
    for (int i = 0; i < DD; ++i) {
        float uu = ub[i * DD + l];
        float x  = fminf(fmaxf(uu, lo), hi);
        float inner = (float)fast_log((double)x, tbl);
        float outer = (float)fast_log((double)(-inner), tbl);
        float sc = gamma[i * DD + l] + (-outer);
        colv[i] = -sc;                       // cost[i][l], constant-index insert
    }

    // ---- solve (literal reference trajectory, r11) ----
    float v  = 0.0f;  // v[l+1]
    float ud = 0.0f;  // u[l+1]
    int   p  = 0;     // p[l+1] (1-based row matched to column l+1; 0 = none)

#pragma clang loop unroll(disable)
    for (int i = 0; i < DD; ++i) {
        float minv = BIGF;
        int   way  = 0;
        bool  used = false;
        bool  inTree = (l == i);      // row i+1 enters tree via virtual col 0
        int   j0 = 0;
        float c    = colv[__builtin_amdgcn_readfirstlane(i)];  // row i, uniform idx
        float u_i0 = bcastf(ud, i);   // u[i+1]

#pragma clang loop unroll(disable)
        for (int it = 0; it <= DD; ++it) {
            float cur = (c - u_i0) - v;            // ((cost - u) - v), as reference
            bool cc = (!used) && (cur < minv);
            minv = cc ? cur : minv;
            way  = cc ? j0  : way;

            float masked = used ? BIGF : minv;     // ref: where(used, BIG, minv)
            float delta = wave_min64(masked);
            unsigned long long tie = __ballot(masked == delta);
            int j1 = (int)__builtin_ctzll(tie) + 1; // first-index tie-break
            j1 = __builtin_amdgcn_readfirstlane(j1);
            int pj1 = bcasti(p, j1 - 1);

            // next row from registers (uniform dynamic extract -> movrels);
            // lane pj1-1 not yet inTree, so reading its ud here is exact (r6)
            int nrow = __builtin_amdgcn_readfirstlane((pj1 != 0 ? pj1 : 1) - 1);
            float cn = colv[nrow];
            float un = bcastf(ud, nrow);

            // dual updates: literal where()-forms
            float udn = ud + delta;
            float vn  = v - delta;
            float mn  = minv - delta;
            ud   = inTree ? udn : ud;
            v    = used   ? vn  : v;
            minv = used   ? minv : mn;

            used = used || (l == (j1 - 1));
            j0 = j1;
            if (pj1 == 0) break;
            c = cn; u_i0 = un;
            inTree = inTree || (l == (pj1 - 1));
        }

        // ---- augment along way[] chain ----
#pragma clang loop unroll(disable)
        while (j0 != 0) {
            int jn = bcasti(way, j0 - 1);
            int pn = (jn == 0) ? (i + 1) : bcasti(p, jn - 1);
            if (l == (j0 - 1)) p = pn;
            j0 = jn;
        }
    }

    // ---- write one-hot permutation: out[b][p-1][l] = 1 ----
    float* ob = out + (size_t)b * (DD * DD);
    const int prow = p - 1;
#pragma clang loop unroll(disable)
    for (int r = 0; r < DD; ++r) {
        ob[r * DD + l] = (prow == r) ? 1.0f : 0.0f;
    }
}

extern "C" void kernel_launch(void* const* d_in, const int* in_sizes, int n_in,
                              void* d_out, int out_size, void* d_ws, size_t ws_size,
                              hipStream_t stream) {
    const float* gamma = (const float*)d_in[0];
    const float* u     = (const float*)d_in[1];
    float* out = (float*)d_out;
    const int nsamp = in_sizes[1] / (DD * DD);

    lap64_fused<<<dim3(nsamp), dim3(64), 0, stream>>>(gamma, u, out, nsamp);
}

// Round 13
// 463.803 us; speedup vs baseline: 12.3520x; 12.3520x over previous
//
#include <hip/hip_runtime.h>
#include <math.h>

#define DD 64
#define BIGF 1.0e9f

// uniform-lane broadcast via v_readlane (no DS pipe)
__device__ __forceinline__ float bcastf(float x, int lane) {
    return __builtin_bit_cast(float, __builtin_amdgcn_readlane(__builtin_bit_cast(int, x), lane));
}
__device__ __forceinline__ int bcasti(int x, int lane) {
    return __builtin_amdgcn_readlane(x, lane);
}

// full-wave64 min via DPP (pure VALU): row_shr 1/2/4/8 + row_bcast15/31.
__device__ __forceinline__ float wave_min64(float x) {
#define STEPD(ctrl)                                                                \
    {                                                                              \
        int _t = __builtin_amdgcn_update_dpp(__builtin_bit_cast(int, x),           \
                                             __builtin_bit_cast(int, x),           \
                                             ctrl, 0xF, 0xF, false);               \
        x = fminf(x, __builtin_bit_cast(float, _t));                               \
    }
    STEPD(0x111)  // row_shr:1
    STEPD(0x112)  // row_shr:2
    STEPD(0x114)  // row_shr:4
    STEPD(0x118)  // row_shr:8
    STEPD(0x142)  // row_bcast:15
    STEPD(0x143)  // row_bcast:31
#undef STEPD
    return bcastf(x, 63);
}

// ---- fast f64 log (r9..r11, proven absmax 0.0): table + degree-6 log1p ----
__device__ __forceinline__ double fast_log(double d, const double2* __restrict__ tbl) {
    long long bits = __double_as_longlong(d);
    int e = (int)(bits >> 52) - 1023;
    double m = __longlong_as_double((bits & 0x000FFFFFFFFFFFFFLL) | 0x3FF0000000000000LL);
    int idx = (int)(bits >> 45) & 127;
    double2 t = tbl[idx];                 // t.x = inv_c (rounded), t.y = -log(inv_c)
    double r  = fma(m, t.x, -1.0);
    double r2 = r * r;
    double q = fma(r, -1.0 / 6.0, 0.2);
    q = fma(q, r, -0.25);
    q = fma(q, r, 1.0 / 3.0);
    q = fma(q, r, -0.5);
    double res = fma(q, r2, r);           // log1p(r)
    return fma((double)e, 0.69314718055994530942, t.y + res);
}

// ---- Stage: cost = -(gamma + gumbel), gumbel = -log(-log(clip(u))) ----
__global__ __launch_bounds__(256) void stage_kernel(
    const float* __restrict__ gamma,
    const float* __restrict__ uin,
    float* __restrict__ cost,
    int total4)
{
    __shared__ double2 tbl[128];
    {
        int t = threadIdx.x;
        if (t < 128) {
            double c = 1.0 + (double)(2 * t + 1) * (1.0 / 256.0);
            double inv = 1.0 / c;
            tbl[t].x = inv;
            tbl[t].y = -log(inv);
        }
    }
    __syncthreads();

    const float lo = 1e-20f;
    const float hi = (float)(1.0 - 1e-7);
    const int stride = gridDim.x * blockDim.x;

    for (int idx = blockIdx.x * blockDim.x + threadIdx.x; idx < total4; idx += stride) {
        float4 u4 = ((const float4*)uin)[idx];
        int e = idx << 2;
        const float4 g4 = *(const float4*)(gamma + (e & (DD * DD - 1)));

        float uu[4] = {u4.x, u4.y, u4.z, u4.w};
        float gg[4] = {g4.x, g4.y, g4.z, g4.w};
        float rr[4];
#pragma unroll
        for (int k = 0; k < 4; ++k) {
            float x = fminf(fmaxf(uu[k], lo), hi);
            float inner = (float)fast_log((double)x, tbl);
            float outer = (float)fast_log((double)(-inner), tbl);
            float sc = gg[k] + (-outer);
            rr[k] = -sc;
        }
        float4 r4 = {rr[0], rr[1], rr[2], rr[3]};
        ((float4*)cost)[idx] = r4;
    }
}

// ---- ILP-2 JV solver: 4-wave blocks, each wave solves TWO samples ----
// interleaved in one basic block (independent progress; r5-proven merged
// loop + r11 literal-where STEP). Full chain residency: 1024 blocks x 4
// waves x 2 chains = 32 chains/CU; the per-CU drain tail becomes a max
// over 16 pair-sums instead of 32 singles (~26% -> ~16% idle predicted).
// After a sample finishes, its dead STEPs are harmless: p is a complete
// matching (pj1 != 0 always), all values stay finite, p never rewritten.

#define STEP(S) do {                                                         \
    float cur = (c##S - u##S) - v##S;                                        \
    bool cc = (!used##S) && (cur < minv##S);                                 \
    minv##S = cc ? cur : minv##S;                                            \
    way##S  = cc ? j0##S : way##S;                                           \
    float masked = used##S ? BIGF : minv##S;   /* ref: where(used,BIG,minv)*/\
    float delta = wave_min64(masked);                                        \
    unsigned long long tie = __ballot(masked == delta);                      \
    int j1 = (int)__builtin_ctzll(tie) + 1;    /* first-index tie-break */   \
    pj1##S = bcasti(p##S, j1 - 1);                                           \
    int nrow = (pj1##S != 0 ? pj1##S : 1) - 1;                               \
    float cn = cb##S[nrow * DD + l];           /* prefetch next row */       \
    float un = bcastf(ud##S, nrow);            /* lane nrow not yet inTree */\
    float udn = ud##S + delta;                                               \
    float vn  = v##S - delta;                                                \
    float mn  = minv##S - delta;                                             \
    ud##S   = inTree##S ? udn : ud##S;                                       \
    v##S    = used##S   ? vn  : v##S;                                        \
    minv##S = used##S   ? minv##S : mn;                                      \
    used##S   = used##S   || (l == (j1 - 1));                                \
    inTree##S = inTree##S || (l == (pj1##S - 1));                            \
    j0##S = j1;                                                              \
    c##S = cn; u##S = un;                                                    \
} while (0)

#define AUG(S) do {                                                          \
    int jj = j0##S;                                                          \
    _Pragma("clang loop unroll(disable)")                                    \
    while (jj != 0) {                                                        \
        int jn = bcasti(way##S, jj - 1);                                     \
        int pn = (jn == 0) ? (i##S + 1) : bcasti(p##S, jn - 1);              \
        if (l == (jj - 1)) p##S = pn;                                        \
        jj = jn;                                                             \
    }                                                                        \
} while (0)

#define ROWNEXT(S) do {                                                      \
    ++i##S;                                                                  \
    if (i##S >= DD) {                                                        \
        const int prow = p##S - 1;                                           \
        _Pragma("clang loop unroll(disable)")                                \
        for (int r = 0; r < DD; ++r)                                         \
            cb##S[r * DD + l] = (prow == r) ? 1.0f : 0.0f;                   \
        done##S = true;                                                      \
    } else {                                                                 \
        minv##S = BIGF; way##S = 0; used##S = false;                         \
        inTree##S = (l == i##S); j0##S = 0;                                  \
        c##S = cb##S[i##S * DD + l];                                         \
        u##S = bcastf(ud##S, i##S);                                          \
    }                                                                        \
} while (0)

__global__ __launch_bounds__(256, 8) void lap64_ilp2(float* __restrict__ cost, int nsamp)
{
    const int l = threadIdx.x & 63;
    const int widx = blockIdx.x * 4 + (threadIdx.x >> 6);
    const int bA = 2 * widx;
    const int bB = 2 * widx + 1;
    if (bA >= nsamp) return;
    const bool haveB = (bB < nsamp);
    float* cbA = cost + (size_t)bA * (DD * DD);
    float* cbB = cost + (size_t)(haveB ? bB : bA) * (DD * DD);

    float vA = 0.f, udA = 0.f, minvA = BIGF, cA = cbA[l], uA = 0.f;
    int   pA = 0, wayA = 0, j0A = 0, iA = 0, pj1A = 1;
    bool  usedA = false, inTreeA = (l == 0), doneA = false;

    float vB = 0.f, udB = 0.f, minvB = BIGF, cB = cbB[l], uB = 0.f;
    int   pB = 0, wayB = 0, j0B = 0, iB = 0, pj1B = 1;
    bool  usedB = false, inTreeB = (l == 0), doneB = !haveB;

#pragma clang loop unroll(disable)
    while (!(doneA && doneB)) {
        STEP(A);
        STEP(B);
        if (!doneA && pj1A == 0) { AUG(A); ROWNEXT(A); }
        if (!doneB && pj1B == 0) { AUG(B); ROWNEXT(B); }
    }
}

extern "C" void kernel_launch(void* const* d_in, const int* in_sizes, int n_in,
                              void* d_out, int out_size, void* d_ws, size_t ws_size,
                              hipStream_t stream) {
    const float* gamma = (const float*)d_in[0];
    const float* u     = (const float*)d_in[1];
    float* out = (float*)d_out;
    const int nsamp = in_sizes[1] / (DD * DD);
    const int total4 = nsamp * DD * DD / 4;

    stage_kernel<<<dim3(4096), dim3(256), 0, stream>>>(gamma, u, out, total4);
    const int nwave = (nsamp + 1) / 2;           // 4096
    lap64_ilp2<<<dim3((nwave + 3) / 4), dim3(256), 0, stream>>>(out, nsamp);
}

// Round 14
// 352.935 us; speedup vs baseline: 16.2322x; 1.3141x over previous
//
#include <hip/hip_runtime.h>
#include <math.h>

#define DD 64
#define BIGF 1.0e9f

// uniform-lane broadcast via v_readlane (no DS pipe)
__device__ __forceinline__ float bcastf(float x, int lane) {
    return __builtin_bit_cast(float, __builtin_amdgcn_readlane(__builtin_bit_cast(int, x), lane));
}
__device__ __forceinline__ int bcasti(int x, int lane) {
    return __builtin_amdgcn_readlane(x, lane);
}

// full-wave64 min via DPP (pure VALU): row_shr 1/2/4/8 + row_bcast15/31.
__device__ __forceinline__ float wave_min64(float x) {
#define STEPD(ctrl)                                                                \
    {                                                                              \
        int _t = __builtin_amdgcn_update_dpp(__builtin_bit_cast(int, x),           \
                                             __builtin_bit_cast(int, x),           \
                                             ctrl, 0xF, 0xF, false);               \
        x = fminf(x, __builtin_bit_cast(float, _t));                               \
    }
    STEPD(0x111)  // row_shr:1
    STEPD(0x112)  // row_shr:2
    STEPD(0x114)  // row_shr:4
    STEPD(0x118)  // row_shr:8
    STEPD(0x142)  // row_bcast:15
    STEPD(0x143)  // row_bcast:31
#undef STEPD
    return bcastf(x, 63);
}

// ---- fast f64 log (r9..r13, proven absmax 0.0): table + degree-6 log1p ----
__device__ __forceinline__ double fast_log(double d, const double2* __restrict__ tbl) {
    long long bits = __double_as_longlong(d);
    int e = (int)(bits >> 52) - 1023;
    double m = __longlong_as_double((bits & 0x000FFFFFFFFFFFFFLL) | 0x3FF0000000000000LL);
    int idx = (int)(bits >> 45) & 127;
    double2 t = tbl[idx];                 // t.x = inv_c (rounded), t.y = -log(inv_c)
    double r  = fma(m, t.x, -1.0);
    double r2 = r * r;
    double q = fma(r, -1.0 / 6.0, 0.2);
    q = fma(q, r, -0.25);
    q = fma(q, r, 1.0 / 3.0);
    q = fma(q, r, -0.5);
    double res = fma(q, r2, r);           // log1p(r)
    return fma((double)e, 0.69314718055994530942, t.y + res);
}

// ---- Stage: cost = -(gamma + gumbel), gumbel = -log(-log(clip(u))) ----
__global__ __launch_bounds__(256) void stage_kernel(
    const float* __restrict__ gamma,
    const float* __restrict__ uin,
    float* __restrict__ cost,
    int total4)
{
    __shared__ double2 tbl[128];
    {
        int t = threadIdx.x;
        if (t < 128) {
            double c = 1.0 + (double)(2 * t + 1) * (1.0 / 256.0);
            double inv = 1.0 / c;
            tbl[t].x = inv;
            tbl[t].y = -log(inv);
        }
    }
    __syncthreads();

    const float lo = 1e-20f;
    const float hi = (float)(1.0 - 1e-7);
    const int stride = gridDim.x * blockDim.x;

    for (int idx = blockIdx.x * blockDim.x + threadIdx.x; idx < total4; idx += stride) {
        float4 u4 = ((const float4*)uin)[idx];
        int e = idx << 2;
        const float4 g4 = *(const float4*)(gamma + (e & (DD * DD - 1)));

        float uu[4] = {u4.x, u4.y, u4.z, u4.w};
        float gg[4] = {g4.x, g4.y, g4.z, g4.w};
        float rr[4];
#pragma unroll
        for (int k = 0; k < 4; ++k) {
            float x = fminf(fmaxf(uu[k], lo), hi);
            float inner = (float)fast_log((double)x, tbl);
            float outer = (float)fast_log((double)(-inner), tbl);
            float sc = gg[k] + (-outer);
            rr[k] = -sc;
        }
        float4 r4 = {rr[0], rr[1], rr[2], rr[3]};
        ((float4*)cost)[idx] = r4;
    }
}

// ---- LAP: 256-thread blocks = 4 independent waves, 1 sample each (r11). ----
// Lane l owns column j=l+1 state (v,minv,way,p,used) and row r=l+1 dual u.
// Literal f32 replication of the reference JV trajectory (absmax 0.0,
// r1..r13). New in r14: next-row-start prefetch hoisted to the top of the
// search (covers the drain-phase cold stall), and a float4 one-hot epilogue.
__global__ __launch_bounds__(256, 8) void lap64_kernel(float* __restrict__ cost, int nsamp)
{
    const int l = threadIdx.x & 63;
    const int b = blockIdx.x * 4 + (threadIdx.x >> 6);
    if (b >= nsamp) return;
    float* cb = cost + (size_t)b * (DD * DD);

    float v  = 0.0f;  // v[l+1]
    float ud = 0.0f;  // u[l+1]
    int   p  = 0;     // p[l+1] (1-based row matched to column l+1; 0 = none)

    float cnext = cb[l];              // row 0 start (prefetched)

#pragma clang loop unroll(disable)
    for (int i = 0; i < DD; ++i) {
        float minv = BIGF;
        int   way  = 0;
        bool  used = false;
        bool  inTree = (l == i);      // row i+1 enters tree via virtual col 0
        int   j0 = 0;
        float c = cnext;              // row i (prefetched last iteration)
        // prefetch next row-start NOW: ~search-length of slack instead of 0
        if (i + 1 < DD) cnext = cb[(i + 1) * DD + l];
        float u_i0 = bcastf(ud, i);   // u[i+1]

#pragma clang loop unroll(disable)
        for (int it = 0; it <= DD; ++it) {
            float cur = (c - u_i0) - v;            // ((cost - u) - v), as reference
            bool cc = (!used) && (cur < minv);
            minv = cc ? cur : minv;
            way  = cc ? j0  : way;

            float masked = used ? BIGF : minv;     // ref: where(used, BIG, minv)
            float delta = wave_min64(masked);
            unsigned long long tie = __ballot(masked == delta);
            int j1 = (int)__builtin_ctzll(tie) + 1; // first-index tie-break
            int pj1 = bcasti(p, j1 - 1);

            // prefetch next tree row + next u[i0] (lane pj1-1 not yet inTree)
            if (pj1 != 0) {
                c    = cb[(pj1 - 1) * DD + l];
                u_i0 = bcastf(ud, pj1 - 1);
            }

            // dual updates: literal where()-forms
            float udn = ud + delta;
            float vn  = v - delta;
            float mn  = minv - delta;
            ud   = inTree ? udn : ud;
            v    = used   ? vn  : v;
            minv = used   ? minv : mn;

            used = used || (l == (j1 - 1));
            j0 = j1;
            if (pj1 == 0) break;
            inTree = inTree || (l == (pj1 - 1));
        }

        // ---- augment along way[] chain ----
#pragma clang loop unroll(disable)
        while (j0 != 0) {
            int jn = bcasti(way, j0 - 1);
            int pn = (jn == 0) ? (i + 1) : bcasti(p, jn - 1);
            if (l == (j0 - 1)) p = pn;
            j0 = jn;
        }
    }

    // ---- one-hot epilogue, float4: out[r][c] = (prow_c == r) ----
    const int prow = p - 1;
    const int col0 = (4 * l) & 63;                 // this lane's 4 columns
    int pr0 = __shfl(prow, col0 + 0);
    int pr1 = __shfl(prow, col0 + 1);
    int pr2 = __shfl(prow, col0 + 2);
    int pr3 = __shfl(prow, col0 + 3);
#pragma clang loop unroll(disable)
    for (int t = 0; t < 16; ++t) {
        int row = t * 4 + (l >> 4);
        float4 val = {(pr0 == row) ? 1.0f : 0.0f,
                      (pr1 == row) ? 1.0f : 0.0f,
                      (pr2 == row) ? 1.0f : 0.0f,
                      (pr3 == row) ? 1.0f : 0.0f};
        ((float4*)cb)[row * (DD / 4) + (col0 >> 2)] = val;
    }
}

extern "C" void kernel_launch(void* const* d_in, const int* in_sizes, int n_in,
                              void* d_out, int out_size, void* d_ws, size_t ws_size,
                              hipStream_t stream) {
    const float* gamma = (const float*)d_in[0];
    const float* u     = (const float*)d_in[1];
    float* out = (float*)d_out;
    const int nsamp = in_sizes[1] / (DD * DD);
    const int total4 = nsamp * DD * DD / 4;

    stage_kernel<<<dim3(4096), dim3(256), 0, stream>>>(gamma, u, out, total4);
    lap64_kernel<<<dim3((nsamp + 3) / 4), dim3(256), 0, stream>>>(out, nsamp);
}